// Round 1
// baseline (445.325 us; speedup 1.0000x reference)
//
#include <hip/hip_runtime.h>

#define NUM_EMBED 1024
#define EMBED_DIM 256
#define BATCH 16
#define SPATIAL 4096          // 64*64
#define NROWS 65536           // BATCH*SPATIAL
#define EMBED_ELEMS 16777216  // BATCH*EMBED_DIM*SPATIAL

// orderable key for fp32: monotone map float -> uint32
__device__ __forceinline__ unsigned fkey(float f) {
  unsigned u = __float_as_uint(f);
  return (u & 0x80000000u) ? ~u : (u | 0x80000000u);
}

// ---------------- init: packed mins, used flags, codebook norms ----------------
__global__ __launch_bounds__(256) void k_init(const float* __restrict__ cb,
                                              unsigned long long* __restrict__ packed,
                                              int* __restrict__ used,
                                              float* __restrict__ cnorm) {
  int bid = blockIdx.x, tid = threadIdx.x;
  if (bid < 256) {
    packed[bid * 256 + tid] = ~0ull;
  } else if (bid == 256) {
    used[tid] = 0; used[tid + 256] = 0; used[tid + 512] = 0; used[tid + 768] = 0;
  } else {
    // blocks 257..320: 16 codes per block, 16 lanes per code
    int c = (bid - 257) * 16 + (tid >> 4);
    int l = tid & 15;
    const float4* p = (const float4*)(cb + c * EMBED_DIM + l * 16);
    float s = 0.f;
#pragma unroll
    for (int j = 0; j < 4; ++j) {
      float4 v = p[j];
      s += v.x * v.x + v.y * v.y + v.z * v.z + v.w * v.w;
    }
#pragma unroll
    for (int off = 1; off < 16; off <<= 1) s += __shfl_xor(s, off, 16);
    if (l == 0) cnorm[c] = s;
  }
}

// ---------------- GEMM + argmin: score = |c|^2 - 2 x.c ----------------
// grid 4096 = 512 m-tiles x 8 n-tiles; XCD-swizzled so one XCD sees all 8
// n-tiles of the same A panel (A reuse in its private L2).
__global__ __launch_bounds__(256) void k_gemm(const float* __restrict__ in,
                                              const float* __restrict__ cb,
                                              const float* __restrict__ cnorm,
                                              unsigned long long* __restrict__ packed) {
  __shared__ float As[8][128];
  __shared__ float Bs[8][128];
  int bid = blockIdx.x;
  int xcd = bid & 7;
  int j = bid >> 3;                 // 0..511
  int mtile = xcd * 64 + (j >> 3);  // 0..511
  int ntile = j & 7;                // 0..7
  int m0 = mtile << 7;
  int n0 = ntile << 7;
  int batch = m0 >> 12;
  int s0 = m0 & 4095;
  const float* Abase = in + batch * (EMBED_DIM * SPATIAL) + s0;
  int tid = threadIdx.x;
  int tx = tid & 15, ty = tid >> 4;

  float acc[2][2][4][4] = {};

  int ak = tid >> 5;            // 0..7   (d within chunk)
  int asl = (tid & 31) << 2;    // 0..124 (spatial, float4)
  int bn = tid >> 1;            // 0..127 (code within tile)
  int bkq = (tid & 1) << 2;     // 0 or 4 (d within chunk, float4)
  const float* aptr = Abase + ak * SPATIAL + asl;
  const float* bptr = cb + (n0 + bn) * EMBED_DIM + bkq;

  for (int kc = 0; kc < EMBED_DIM; kc += 8) {
    float4 av = *(const float4*)(aptr + kc * SPATIAL);
    float4 bv = *(const float4*)(bptr + kc);
    *(float4*)&As[ak][asl] = av;
    Bs[bkq + 0][bn] = bv.x; Bs[bkq + 1][bn] = bv.y;
    Bs[bkq + 2][bn] = bv.z; Bs[bkq + 3][bn] = bv.w;
    __syncthreads();
#pragma unroll
    for (int k = 0; k < 8; ++k) {
      float a0[4], a1[4], b0[4], b1[4];
      *(float4*)a0 = *(const float4*)&As[k][4 * ty];
      *(float4*)a1 = *(const float4*)&As[k][64 + 4 * ty];
      *(float4*)b0 = *(const float4*)&Bs[k][4 * tx];
      *(float4*)b1 = *(const float4*)&Bs[k][64 + 4 * tx];
#pragma unroll
      for (int mi = 0; mi < 4; ++mi)
#pragma unroll
        for (int ni = 0; ni < 4; ++ni) {
          acc[0][0][mi][ni] += a0[mi] * b0[ni];
          acc[0][1][mi][ni] += a0[mi] * b1[ni];
          acc[1][0][mi][ni] += a1[mi] * b0[ni];
          acc[1][1][mi][ni] += a1[mi] * b1[ni];
        }
    }
    __syncthreads();
  }

  // epilogue: per-row min over this block's 128 codes, then atomicMin
#pragma unroll
  for (int im = 0; im < 2; ++im)
#pragma unroll
    for (int mi = 0; mi < 4; ++mi) {
      unsigned long long best = ~0ull;
#pragma unroll
      for (int in_ = 0; in_ < 2; ++in_)
#pragma unroll
        for (int ni = 0; ni < 4; ++ni) {
          int n = n0 + in_ * 64 + 4 * tx + ni;
          float s = cnorm[n] - 2.0f * acc[im][in_][mi][ni];
          unsigned long long p = ((unsigned long long)fkey(s) << 32) | (unsigned)n;
          best = p < best ? p : best;
        }
#pragma unroll
      for (int off = 1; off < 16; off <<= 1) {
        unsigned long long o = __shfl_xor(best, off, 16);
        best = o < best ? o : best;
      }
      if (tx == 0) atomicMin(&packed[m0 + im * 64 + 4 * ty + mi], best);
    }
}

// ---------------- finalize rows: idx out (as float), idx int, used ----------------
__global__ __launch_bounds__(256) void k_rows(const unsigned long long* __restrict__ packed,
                                              float* __restrict__ out_idx,
                                              int* __restrict__ idxi,
                                              int* __restrict__ used) {
  int row = blockIdx.x * 256 + threadIdx.x;
  int idx = (int)(packed[row] & 0xffffffffull);
  out_idx[row] = (float)idx;
  idxi[row] = idx;
  used[idx] = 1;  // benign race: all writers store 1
}

// ---------------- gather embed + MSE partial sums ----------------
__global__ __launch_bounds__(256) void k_gather(const float* __restrict__ in,
                                                const float* __restrict__ cb,
                                                const int* __restrict__ idxi,
                                                float* __restrict__ embed_out,
                                                double* __restrict__ partials) {
  int tid = threadIdx.x;
  float lsum = 0.f;
#pragma unroll
  for (int it = 0; it < 4; ++it) {
    int gid = (it * 4096 + blockIdx.x) * 256 + tid;  // float4-group id
    int b = gid >> 18;        // / (256*1024)
    int r = gid & 262143;
    int d = r >> 10;
    int s4 = r & 1023;
    int4 id4 = *(const int4*)(idxi + (b << 12) + (s4 << 2));
    int off = ((b * EMBED_DIM + d) << 12) + (s4 << 2);
    float4 x = *(const float4*)(in + off);
    float4 e;
    e.x = cb[id4.x * EMBED_DIM + d];
    e.y = cb[id4.y * EMBED_DIM + d];
    e.z = cb[id4.z * EMBED_DIM + d];
    e.w = cb[id4.w * EMBED_DIM + d];
    *(float4*)(embed_out + off) = e;
    float dx = e.x - x.x, dy = e.y - x.y, dz = e.z - x.z, dw = e.w - x.w;
    lsum += dx * dx + dy * dy + dz * dz + dw * dw;
  }
#pragma unroll
  for (int off = 1; off < 64; off <<= 1) lsum += __shfl_xor(lsum, off, 64);
  __shared__ float wsum[4];
  if ((tid & 63) == 0) wsum[tid >> 6] = lsum;
  __syncthreads();
  if (tid == 0)
    partials[blockIdx.x] = (double)(wsum[0] + wsum[1] + wsum[2] + wsum[3]);
}

// ---------------- tail: loss scalar + new_last_used ----------------
__global__ __launch_bounds__(256) void k_tail(const double* __restrict__ partials,
                                              const int* __restrict__ used,
                                              const int* __restrict__ last_used,
                                              float* __restrict__ out_loss,
                                              float* __restrict__ out_lu) {
  int tid = threadIdx.x;
  double s = 0.0;
  for (int i = tid; i < 4096; i += 256) s += partials[i];
#pragma unroll
  for (int off = 1; off < 64; off <<= 1) s += __shfl_xor(s, off, 64);
  __shared__ double sd[4];
  if ((tid & 63) == 0) sd[tid >> 6] = s;
  __syncthreads();
  if (tid == 0) {
    double total = sd[0] + sd[1] + sd[2] + sd[3];
    out_loss[0] = (float)(1.25 * total / (double)EMBED_ELEMS);
  }
  for (int i = tid; i < NUM_EMBED; i += 256)
    out_lu[i] = used[i] ? 0.0f : (float)(last_used[i] + 1);
}

extern "C" void kernel_launch(void* const* d_in, const int* in_sizes, int n_in,
                              void* d_out, int out_size, void* d_ws, size_t ws_size,
                              hipStream_t stream) {
  const float* in = (const float*)d_in[0];
  const float* cb = (const float*)d_in[1];
  const int* last_used = (const int*)d_in[2];

  float* out = (float*)d_out;
  float* out_idx = out;                       // 65536
  float* embed_out = out + NROWS;             // 16777216
  float* out_loss = embed_out + EMBED_ELEMS;  // 1
  float* out_lu = out_loss + 1;               // 1024

  unsigned long long* packed = (unsigned long long*)d_ws;  // 65536 u64
  double* partials = (double*)(packed + NROWS);            // 4096 doubles
  int* idxi = (int*)(partials + 4096);                     // 65536 int
  int* used = idxi + NROWS;                                // 1024 int
  float* cnorm = (float*)(used + NUM_EMBED);               // 1024 float

  hipLaunchKernelGGL(k_init, dim3(321), dim3(256), 0, stream, cb, packed, used, cnorm);
  hipLaunchKernelGGL(k_gemm, dim3(4096), dim3(256), 0, stream, in, cb, cnorm, packed);
  hipLaunchKernelGGL(k_rows, dim3(256), dim3(256), 0, stream, packed, out_idx, idxi, used);
  hipLaunchKernelGGL(k_gather, dim3(4096), dim3(256), 0, stream, in, cb, idxi, embed_out, partials);
  hipLaunchKernelGGL(k_tail, dim3(1), dim3(256), 0, stream, partials, used, last_used, out_loss, out_lu);
}

// Round 2
// 248.341 us; speedup vs baseline: 1.7932x; 1.7932x over previous
//
#include <hip/hip_runtime.h>

#define NUM_EMBED 1024
#define EMBED_DIM 256
#define SPATIAL 4096          // 64*64
#define NROWS 65536           // 16*4096
#define EMBED_ELEMS 16777216  // 16*256*4096
#define MARGIN 0.1f

typedef _Float16 half8 __attribute__((ext_vector_type(8)));
typedef _Float16 half4 __attribute__((ext_vector_type(4)));
typedef float f32x4 __attribute__((ext_vector_type(4)));

__device__ __forceinline__ unsigned fkey(float f) {
  unsigned u = __float_as_uint(f);
  return (u & 0x80000000u) ? ~u : (u | 0x80000000u);
}

// ---------------- init: packed mins, used, flagcount, codebook norms ----------------
__global__ __launch_bounds__(256) void k_init(const float* __restrict__ cb,
                                              unsigned long long* __restrict__ packed,
                                              int* __restrict__ used,
                                              int* __restrict__ flagcount,
                                              float* __restrict__ cnorm) {
  int bid = blockIdx.x, tid = threadIdx.x;
  if (bid < 256) {
    packed[bid * 256 + tid] = ~0ull;
  } else if (bid == 256) {
    used[tid] = 0; used[tid + 256] = 0; used[tid + 512] = 0; used[tid + 768] = 0;
    if (tid == 0) *flagcount = 0;
  } else {
    int c = (bid - 257) * 16 + (tid >> 4);
    int l = tid & 15;
    const float4* p = (const float4*)(cb + c * EMBED_DIM + l * 16);
    float s = 0.f;
#pragma unroll
    for (int j = 0; j < 4; ++j) {
      float4 v = p[j];
      s += v.x * v.x + v.y * v.y + v.z * v.z + v.w * v.w;
    }
#pragma unroll
    for (int off = 1; off < 16; off <<= 1) s += __shfl_xor(s, off, 16);
    if (l == 0) cnorm[c] = s;
  }
}

// ---------------- fp16 MFMA screening: per-row min1/min2 over all 1024 codes ----------------
// block: 128 rows x 1024 codes (4 chunks of 256). 4 waves; wave = 64 codes x 128 rows.
// X resident in LDS fp16 (swizzled [s][k]); codebook staged per k-step (reg prefetch).
__global__ __launch_bounds__(256, 2) void k_score(const float* __restrict__ in,
                                                  const float* __restrict__ cb,
                                                  const float* __restrict__ cnorm,
                                                  float* __restrict__ out_idx,
                                                  int* __restrict__ idxi,
                                                  int* __restrict__ flagged,
                                                  int* __restrict__ flagcount) {
  __shared__ _Float16 Xs[32768];  // 64 KB: [128 s][256 k], byte = s*512 + ((k*2)^((s&31)<<4))
  __shared__ _Float16 As[8192];   // 16 KB: [256 code][32 k], byte = c*64 + ((k*2)^((c&3)<<4))
  int tid = threadIdx.x;
  int lane = tid & 63;
  int wave = tid >> 6;
  int ln = lane & 15;
  int kg = (lane >> 4) << 4;  // byte offset of this lane-group's 8-halves k slice
  int r0 = blockIdx.x << 7;
  const float* Ain = in + ((r0 >> 12) * (EMBED_DIM * SPATIAL)) + (r0 & 4095);

  // ---- stage X (fp32 -> fp16, transposed to [s][k], swizzled) ----
  {
    int sl = tid & 127;
    int kh = (tid >> 7) << 2;  // 0 or 4
    int sw = (sl & 31) << 4;
    for (int kb = 0; kb < 256; kb += 8) {
      int k = kb + kh;
      const float* p = Ain + k * SPATIAL + sl;
      float x0 = p[0];
      float x1 = p[SPATIAL];
      float x2 = p[2 * SPATIAL];
      float x3 = p[3 * SPATIAL];
      half4 v = {(_Float16)x0, (_Float16)x1, (_Float16)x2, (_Float16)x3};
      *(half4*)((char*)Xs + (sl << 9) + ((k << 1) ^ sw)) = v;
    }
  }

  // prefetch A tile for step 0 (cc=0, ks=0): thread t = code t, k 0..31
  float4 pa[8];
  {
    const float4* src = (const float4*)(cb + tid * EMBED_DIM);
#pragma unroll
    for (int j = 0; j < 8; ++j) pa[j] = src[j];
  }
  __syncthreads();  // X visible

  f32x4 acc[4][8] = {};
  float sv1[8], sv2[8];
  int si1[8];
#pragma unroll
  for (int nf = 0; nf < 8; ++nf) { sv1[nf] = 3e38f; sv2[nf] = 3e38f; si1[nf] = 0; }

  int abyte0 = (wave * 64 + ln) * 64 + (kg ^ ((ln & 3) << 4));
  int aswz = (tid & 3) << 4;

  for (int sc = 0; sc < 32; ++sc) {
    int cc = sc >> 3, ks = sc & 7;
    // write A(sc) from prefetch regs
    {
      int base = tid * 64;
#pragma unroll
      for (int kk = 0; kk < 4; ++kk) {
        float4 a = pa[kk * 2], b = pa[kk * 2 + 1];
        half8 h;
        h[0] = (_Float16)a.x; h[1] = (_Float16)a.y; h[2] = (_Float16)a.z; h[3] = (_Float16)a.w;
        h[4] = (_Float16)b.x; h[5] = (_Float16)b.y; h[6] = (_Float16)b.z; h[7] = (_Float16)b.w;
        *(half8*)((char*)As + base + ((kk << 4) ^ aswz)) = h;
      }
    }
    __syncthreads();  // A(sc) visible
    // prefetch A(sc+1)
    if (sc < 31) {
      int nsc = sc + 1;
      const float4* src =
          (const float4*)(cb + ((nsc >> 3) * 256 + tid) * EMBED_DIM + (nsc & 7) * 32);
#pragma unroll
      for (int j = 0; j < 8; ++j) pa[j] = src[j];
    }
    // fragment loads + MFMA
    half8 af[4];
#pragma unroll
    for (int mf = 0; mf < 4; ++mf)
      af[mf] = *(const half8*)((const char*)As + abyte0 + mf * 1024);
#pragma unroll
    for (int nf = 0; nf < 8; ++nf) {
      int sl = nf * 16 + ln;
      half8 bf = *(const half8*)((const char*)Xs + (sl << 9) +
                                 (((ks << 6) + kg) ^ ((sl & 31) << 4)));
#pragma unroll
      for (int mf = 0; mf < 4; ++mf)
        acc[mf][nf] = __builtin_amdgcn_mfma_f32_16x16x32_f16(af[mf], bf, acc[mf][nf], 0, 0, 0);
    }
    if (ks == 7) {
      // epilogue: fold chunk cc's 256 codes into running per-row min1/min2
      float cnv[4][4];
      int cbase = cc * 256 + wave * 64 + ((lane >> 4) << 2);
#pragma unroll
      for (int mf = 0; mf < 4; ++mf)
        *(float4*)cnv[mf] = *(const float4*)(cnorm + cbase + mf * 16);
#pragma unroll
      for (int nf = 0; nf < 8; ++nf) {
        float v1 = 3e38f, v2 = 3e38f;
        int i1 = 0;
#pragma unroll
        for (int mf = 0; mf < 4; ++mf) {
#pragma unroll
          for (int r = 0; r < 4; ++r) {
            float s = cnv[mf][r] - 2.0f * acc[mf][nf][r];
            int c = cbase + mf * 16 + r;
            if (s < v1) { v2 = v1; v1 = s; i1 = c; }
            else if (s < v2) { v2 = s; }
          }
        }
#pragma unroll
        for (int off = 16; off < 64; off <<= 1) {
          float ov1 = __shfl_xor(v1, off);
          float ov2 = __shfl_xor(v2, off);
          int oi = __shfl_xor(i1, off);
          if (ov1 < v1) { v2 = fminf(v1, ov2); v1 = ov1; i1 = oi; }
          else { v2 = fminf(v2, ov1); }
        }
        if (v1 < sv1[nf]) { sv2[nf] = fminf(sv1[nf], v2); sv1[nf] = v1; si1[nf] = i1; }
        else { sv2[nf] = fminf(sv2[nf], v1); }
        f32x4 z = {0.f, 0.f, 0.f, 0.f};
#pragma unroll
        for (int mf = 0; mf < 4; ++mf) acc[mf][nf] = z;
      }
    }
    __syncthreads();  // done reading As before next overwrite
  }

  // ---- cross-wave merge (waves cover disjoint code sets, same rows) ----
  float* mv1 = (float*)As;  // [4 waves][8 nf][16 col]
  float* mv2 = mv1 + 512;
  int* mi1 = (int*)(mv2 + 512);
  if (lane < 16) {
#pragma unroll
    for (int nf = 0; nf < 8; ++nf) {
      int slot = ((wave * 8 + nf) << 4) + lane;
      mv1[slot] = sv1[nf]; mv2[slot] = sv2[nf]; mi1[slot] = si1[nf];
    }
  }
  __syncthreads();
  if (tid < 128) {
    float v1 = 3e38f, v2 = 3e38f;
    int i1 = 0;
    int rhi = tid >> 4, rlo = tid & 15;
#pragma unroll
    for (int w = 0; w < 4; ++w) {
      int slot = ((w * 8 + rhi) << 4) + rlo;
      float ov1 = mv1[slot], ov2 = mv2[slot];
      int oi = mi1[slot];
      if (ov1 < v1) { v2 = fminf(v1, ov2); v1 = ov1; i1 = oi; }
      else { v2 = fminf(v2, ov1); }
    }
    int grow = r0 + tid;
    out_idx[grow] = (float)i1;
    idxi[grow] = i1;
    if (v2 - v1 < MARGIN) {
      int p = atomicAdd(flagcount, 1);
      flagged[p] = grow;
    }
  }
}

// ---------------- exact fp32 re-ranking of flagged rows ----------------
__global__ __launch_bounds__(256) void k_cleanup(const float* __restrict__ in,
                                                 const float* __restrict__ cb,
                                                 const float* __restrict__ cnorm,
                                                 const int* __restrict__ flagged,
                                                 const int* __restrict__ flagcount,
                                                 unsigned long long* __restrict__ packed) {
  __shared__ float xrow[EMBED_DIM];
  int tid = threadIdx.x;
  int nf = *flagcount;
  int chunk = blockIdx.x & 3;
  for (int fi = blockIdx.x >> 2; fi < nf; fi += 256) {
    int row = flagged[fi];
    int batch = row >> 12, s = row & 4095;
    xrow[tid] = in[batch * (EMBED_DIM * SPATIAL) + tid * SPATIAL + s];
    __syncthreads();
    int code = chunk * 256 + tid;
    const float4* crow = (const float4*)(cb + code * EMBED_DIM);
    float dot = 0.f;
#pragma unroll
    for (int k4 = 0; k4 < 64; ++k4) {
      float4 c = crow[k4];
      dot += c.x * xrow[k4 * 4] + c.y * xrow[k4 * 4 + 1] + c.z * xrow[k4 * 4 + 2] +
             c.w * xrow[k4 * 4 + 3];
    }
    float sc = cnorm[code] - 2.0f * dot;
    unsigned long long p = ((unsigned long long)fkey(sc) << 32) | (unsigned)code;
    atomicMin(&packed[fi], p);
    __syncthreads();
  }
}

// ---------------- apply cleanup winners ----------------
__global__ __launch_bounds__(256) void k_fix(const int* __restrict__ flagged,
                                             const int* __restrict__ flagcount,
                                             const unsigned long long* __restrict__ packed,
                                             float* __restrict__ out_idx,
                                             int* __restrict__ idxi) {
  int nf = *flagcount;
  int i = blockIdx.x * 256 + threadIdx.x;
  if (i < nf) {
    int row = flagged[i];
    int idx = (int)(packed[i] & 0xffffffffull);
    out_idx[row] = (float)idx;
    idxi[row] = idx;
  }
}

// ---------------- mark used codes ----------------
__global__ __launch_bounds__(256) void k_used(const int* __restrict__ idxi,
                                              int* __restrict__ used) {
  int gid = blockIdx.x * 256 + threadIdx.x;
  used[idxi[gid]] = 1;
}

// ---------------- gather embed + MSE partial sums ----------------
__global__ __launch_bounds__(256) void k_gather(const float* __restrict__ in,
                                                const float* __restrict__ cb,
                                                const int* __restrict__ idxi,
                                                float* __restrict__ embed_out,
                                                double* __restrict__ partials) {
  int tid = threadIdx.x;
  float lsum = 0.f;
#pragma unroll
  for (int it = 0; it < 4; ++it) {
    int gid = (it * 4096 + blockIdx.x) * 256 + tid;
    int b = gid >> 18;
    int r = gid & 262143;
    int d = r >> 10;
    int s4 = r & 1023;
    int4 id4 = *(const int4*)(idxi + (b << 12) + (s4 << 2));
    int off = ((b * EMBED_DIM + d) << 12) + (s4 << 2);
    float4 x = *(const float4*)(in + off);
    float4 e;
    e.x = cb[id4.x * EMBED_DIM + d];
    e.y = cb[id4.y * EMBED_DIM + d];
    e.z = cb[id4.z * EMBED_DIM + d];
    e.w = cb[id4.w * EMBED_DIM + d];
    *(float4*)(embed_out + off) = e;
    float dx = e.x - x.x, dy = e.y - x.y, dz = e.z - x.z, dw = e.w - x.w;
    lsum += dx * dx + dy * dy + dz * dz + dw * dw;
  }
#pragma unroll
  for (int off = 1; off < 64; off <<= 1) lsum += __shfl_xor(lsum, off, 64);
  __shared__ float wsum[4];
  if ((tid & 63) == 0) wsum[tid >> 6] = lsum;
  __syncthreads();
  if (tid == 0)
    partials[blockIdx.x] = (double)(wsum[0] + wsum[1] + wsum[2] + wsum[3]);
}

// ---------------- tail: loss scalar + new_last_used ----------------
__global__ __launch_bounds__(256) void k_tail(const double* __restrict__ partials,
                                              const int* __restrict__ used,
                                              const int* __restrict__ last_used,
                                              float* __restrict__ out_loss,
                                              float* __restrict__ out_lu) {
  int tid = threadIdx.x;
  double s = 0.0;
  for (int i = tid; i < 4096; i += 256) s += partials[i];
#pragma unroll
  for (int off = 1; off < 64; off <<= 1) s += __shfl_xor(s, off, 64);
  __shared__ double sd[4];
  if ((tid & 63) == 0) sd[tid >> 6] = s;
  __syncthreads();
  if (tid == 0) {
    double total = sd[0] + sd[1] + sd[2] + sd[3];
    out_loss[0] = (float)(1.25 * total / (double)EMBED_ELEMS);
  }
  for (int i = tid; i < NUM_EMBED; i += 256)
    out_lu[i] = used[i] ? 0.0f : (float)(last_used[i] + 1);
}

extern "C" void kernel_launch(void* const* d_in, const int* in_sizes, int n_in,
                              void* d_out, int out_size, void* d_ws, size_t ws_size,
                              hipStream_t stream) {
  const float* in = (const float*)d_in[0];
  const float* cb = (const float*)d_in[1];
  const int* last_used = (const int*)d_in[2];

  float* out = (float*)d_out;
  float* out_idx = out;                        // 65536
  float* embed_out = out + NROWS;              // 16777216
  float* out_loss = embed_out + EMBED_ELEMS;   // 1
  float* out_lu = out_loss + 1;                // 1024

  unsigned long long* packed = (unsigned long long*)d_ws;  // 65536 u64
  double* partials = (double*)(packed + NROWS);            // 4096 double
  int* flagged = (int*)(partials + 4096);                  // 65536 int
  int* flagcount = flagged + NROWS;                        // 16 int (1 used)
  int* idxi = flagcount + 16;                              // 65536 int
  int* used = idxi + NROWS;                                // 1024 int
  float* cnorm = (float*)(used + NUM_EMBED);               // 1024 float

  hipLaunchKernelGGL(k_init, dim3(321), dim3(256), 0, stream, cb, packed, used, flagcount, cnorm);
  hipLaunchKernelGGL(k_score, dim3(512), dim3(256), 0, stream, in, cb, cnorm, out_idx, idxi,
                     flagged, flagcount);
  hipLaunchKernelGGL(k_cleanup, dim3(1024), dim3(256), 0, stream, in, cb, cnorm, flagged,
                     flagcount, packed);
  hipLaunchKernelGGL(k_fix, dim3(256), dim3(256), 0, stream, flagged, flagcount, packed,
                     out_idx, idxi);
  hipLaunchKernelGGL(k_used, dim3(256), dim3(256), 0, stream, idxi, used);
  hipLaunchKernelGGL(k_gather, dim3(4096), dim3(256), 0, stream, in, cb, idxi, embed_out,
                     partials);
  hipLaunchKernelGGL(k_tail, dim3(1), dim3(256), 0, stream, partials, used, last_used,
                     out_loss, out_lu);
}